// Round 1
// baseline (466.998 us; speedup 1.0000x reference)
//
#include <hip/hip_runtime.h>

#define Bq 16
#define Nq 1024
#define Dq 128
#define JB 16   // j-rows per block in the MLP kernel

// ---------------------------------------------------------------------------
// Kernel 1: logits[b][j][0..1] = relu([nodes[b][n] || nodes[b][j]] @ W1 + b1) @ W2 + b2
// Block = 128 threads (thread = output feature k), handles one batch b and JB j's.
// Left-half contribution of W1 is shared across all j -> computed once.
// ---------------------------------------------------------------------------
__global__ __launch_bounds__(128) void logits_kernel(
    const float* __restrict__ nodes, const float* __restrict__ W1,
    const float* __restrict__ b1, const float* __restrict__ W2,
    const float* __restrict__ b2, const int* __restrict__ num_nodes,
    float* __restrict__ logits /* B*N*2 */) {

    const int blk = blockIdx.x;            // b * (N/JB) + jblock
    const int b = blk / (Nq / JB);
    const int j0 = (blk % (Nq / JB)) * JB;
    const int k = threadIdx.x;             // 0..127
    const int n = num_nodes[b];

    __shared__ float xs[(JB + 1) * Dq];    // [0..D): left row; then JB right rows
    __shared__ float hs[JB * Dq];          // relu hidden

    const size_t nb = (size_t)b * Nq * Dq;
    xs[k] = nodes[nb + (size_t)n * Dq + k];
    #pragma unroll
    for (int jj = 0; jj < JB; ++jj)
        xs[(1 + jj) * Dq + k] = nodes[nb + (size_t)(j0 + jj) * Dq + k];
    __syncthreads();

    // Shared (left) contribution: base_k = b1[k] + sum_c left[c] * W1[c][k]
    float base = b1[k];
    for (int c = 0; c < Dq; ++c)
        base = fmaf(xs[c], W1[c * Dq + k], base);

    float acc[JB];
    #pragma unroll
    for (int jj = 0; jj < JB; ++jj) acc[jj] = base;

    // Right contribution: rows 128..255 of W1
    for (int c = 0; c < Dq; ++c) {
        const float w = W1[(Dq + c) * Dq + k];
        #pragma unroll
        for (int jj = 0; jj < JB; ++jj)
            acc[jj] = fmaf(xs[(1 + jj) * Dq + c], w, acc[jj]);
    }

    #pragma unroll
    for (int jj = 0; jj < JB; ++jj)
        hs[jj * Dq + k] = fmaxf(acc[jj], 0.0f);
    __syncthreads();

    // Reduce to logits: 32 threads, each one (jj, m) pair
    if (k < JB * 2) {
        const int jj = k >> 1, m = k & 1;
        float s = b2[m];
        for (int kk = 0; kk < Dq; ++kk)
            s = fmaf(hs[jj * Dq + kk], W2[kk * 2 + m], s);
        logits[((size_t)b * Nq + j0 + jj) * 2 + m] = s;
    }
}

// ---------------------------------------------------------------------------
// Kernel 2: build s (state + cross override) and probs (hard one-hot of s+g).
// One float4 per thread = channel-pairs for (i,j) and (i,j+1).
// ---------------------------------------------------------------------------
__global__ __launch_bounds__(256) void fill_kernel(
    const float* __restrict__ state, const float* __restrict__ gumbel,
    const int* __restrict__ num_nodes, const float* __restrict__ logits,
    float* __restrict__ out_s, float* __restrict__ out_p) {

    const size_t idx = (size_t)blockIdx.x * blockDim.x + threadIdx.x; // float4 idx
    // total float4 = B*N*N/2 = 2^23 ; N*N/2 = 2^19 ; N/2 = 2^9
    const int b = (int)(idx >> 19);
    const int rem = (int)(idx & 524287);
    const int i = rem >> 9;
    const int j = (rem & 511) << 1;
    const int n = num_nodes[b];

    float4 sv = ((const float4*)state)[idx];
    const float4 gm = ((const float4*)gumbel)[idx];

    const float* lg = logits + (size_t)b * Nq * 2;

    if (i == n) {
        // row scatter wins: s[n][j<=n] = logits[j]
        if (j <= n)     { sv.x = lg[j * 2];       sv.y = lg[j * 2 + 1]; }
        if (j + 1 <= n) { sv.z = lg[(j + 1) * 2]; sv.w = lg[(j + 1) * 2 + 1]; }
    } else if (i < n) {
        // col scatter: s[i<=n][n] = logits[i]   (i==n handled above)
        if (j == n)          { sv.x = lg[i * 2]; sv.y = lg[i * 2 + 1]; }
        else if (j + 1 == n) { sv.z = lg[i * 2]; sv.w = lg[i * 2 + 1]; }
    }

    float4 pv;
    const bool k1 = (sv.y + gm.y) > (sv.x + gm.x);
    pv.x = k1 ? 0.0f : 1.0f;  pv.y = k1 ? 1.0f : 0.0f;
    const bool k2 = (sv.w + gm.w) > (sv.z + gm.z);
    pv.z = k2 ? 0.0f : 1.0f;  pv.w = k2 ? 1.0f : 0.0f;

    ((float4*)out_s)[idx] = sv;
    ((float4*)out_p)[idx] = pv;
}

extern "C" void kernel_launch(void* const* d_in, const int* in_sizes, int n_in,
                              void* d_out, int out_size, void* d_ws, size_t ws_size,
                              hipStream_t stream) {
    const float* nodes     = (const float*)d_in[0];
    const float* state     = (const float*)d_in[1];
    const float* W1        = (const float*)d_in[2];
    const float* b1        = (const float*)d_in[3];
    const float* W2        = (const float*)d_in[4];
    const float* b2        = (const float*)d_in[5];
    const int*   num_nodes = (const int*)d_in[6];
    const float* gumbel    = (const float*)d_in[7];

    float* logits = (float*)d_ws;                    // B*N*2 floats = 128 KB
    float* out_s  = (float*)d_out;                   // first output tensor
    float* out_p  = out_s + (size_t)Bq * Nq * Nq * 2; // second output tensor

    logits_kernel<<<Bq * (Nq / JB), 128, 0, stream>>>(
        nodes, W1, b1, W2, b2, num_nodes, logits);

    const size_t total4 = (size_t)Bq * Nq * Nq * 2 / 4; // 8388608
    fill_kernel<<<(int)(total4 / 256), 256, 0, stream>>>(
        state, gumbel, num_nodes, logits, out_s, out_p);
}

// Round 3
// 457.146 us; speedup vs baseline: 1.0216x; 1.0216x over previous
//
#include <hip/hip_runtime.h>

#define Bq 16
#define Nq 1024
#define Dq 128
#define JB 16   // j-rows per block in the MLP kernel

// native vector type (HIP's float4 is a class -> rejected by nontemporal builtins)
typedef float v4f __attribute__((ext_vector_type(4)));

// ---------------------------------------------------------------------------
// Kernel 1: logits[b][j][0..1] = relu([nodes[b][n] || nodes[b][j]] @ W1 + b1) @ W2 + b2
// Block = 128 threads (thread = output feature k), handles one batch b and JB j's.
// Left-half contribution of W1 is shared across all j -> computed once.
// ---------------------------------------------------------------------------
__global__ __launch_bounds__(128) void logits_kernel(
    const float* __restrict__ nodes, const float* __restrict__ W1,
    const float* __restrict__ b1, const float* __restrict__ W2,
    const float* __restrict__ b2, const int* __restrict__ num_nodes,
    float* __restrict__ logits /* B*N*2 */) {

    const int blk = blockIdx.x;            // b * (N/JB) + jblock
    const int b = blk / (Nq / JB);
    const int j0 = (blk % (Nq / JB)) * JB;
    const int k = threadIdx.x;             // 0..127
    const int n = num_nodes[b];

    __shared__ float xs[(JB + 1) * Dq];    // [0..D): left row; then JB right rows
    __shared__ float hs[JB * Dq];          // relu hidden

    const size_t nb = (size_t)b * Nq * Dq;
    xs[k] = nodes[nb + (size_t)n * Dq + k];
    #pragma unroll
    for (int jj = 0; jj < JB; ++jj)
        xs[(1 + jj) * Dq + k] = nodes[nb + (size_t)(j0 + jj) * Dq + k];
    __syncthreads();

    // Shared (left) contribution: base_k = b1[k] + sum_c left[c] * W1[c][k]
    float base = b1[k];
    for (int c = 0; c < Dq; ++c)
        base = fmaf(xs[c], W1[c * Dq + k], base);

    float acc[JB];
    #pragma unroll
    for (int jj = 0; jj < JB; ++jj) acc[jj] = base;

    // Right contribution: rows 128..255 of W1
    for (int c = 0; c < Dq; ++c) {
        const float w = W1[(Dq + c) * Dq + k];
        #pragma unroll
        for (int jj = 0; jj < JB; ++jj)
            acc[jj] = fmaf(xs[(1 + jj) * Dq + c], w, acc[jj]);
    }

    #pragma unroll
    for (int jj = 0; jj < JB; ++jj)
        hs[jj * Dq + k] = fmaxf(acc[jj], 0.0f);
    __syncthreads();

    // Reduce to logits: 32 threads, each one (jj, m) pair
    if (k < JB * 2) {
        const int jj = k >> 1, m = k & 1;
        float s = b2[m];
        for (int kk = 0; kk < Dq; ++kk)
            s = fmaf(hs[jj * Dq + kk], W2[kk * 2 + m], s);
        logits[((size_t)b * Nq + j0 + jj) * 2 + m] = s;
    }
}

// ---------------------------------------------------------------------------
// Kernel 2: one block = one (b, i) row. 256 threads x 2 float4 = 2048 floats
// = N*2 channel values of that row. b/i/n are block-uniform -> scalar branches.
// Non-temporal access: every byte of state/gumbel/out is touched exactly once.
// ---------------------------------------------------------------------------
__global__ __launch_bounds__(256) void fill_kernel(
    const float* __restrict__ state, const float* __restrict__ gumbel,
    const int* __restrict__ num_nodes, const float* __restrict__ logits,
    float* __restrict__ out_s, float* __restrict__ out_p) {

    const int b = blockIdx.x >> 10;        // blockIdx = b*N + i
    const int i = blockIdx.x & (Nq - 1);
    const int n = num_nodes[b];            // block-uniform scalar
    const float* lg = logits + (size_t)b * Nq * 2;

    const size_t rowbase = (size_t)blockIdx.x * (Nq * 2 / 4);  // float4 units
    const v4f* st4 = (const v4f*)state;
    const v4f* gm4 = (const v4f*)gumbel;
    v4f* os4 = (v4f*)out_s;
    v4f* op4 = (v4f*)out_p;

    #pragma unroll
    for (int c = 0; c < 2; ++c) {
        const int f4_in_row = threadIdx.x + c * 256;   // 0..511
        const size_t idx = rowbase + f4_in_row;
        const int jcol = f4_in_row * 2;                // columns jcol, jcol+1

        v4f sv = __builtin_nontemporal_load(&st4[idx]);
        const v4f gm = __builtin_nontemporal_load(&gm4[idx]);

        if (i == n) {
            // row scatter wins: s[n][j<=n] = logits[j]
            if (jcol <= n)     { sv.x = lg[jcol * 2];       sv.y = lg[jcol * 2 + 1]; }
            if (jcol + 1 <= n) { sv.z = lg[(jcol + 1) * 2]; sv.w = lg[(jcol + 1) * 2 + 1]; }
        } else if (i < n) {
            // col scatter: s[i<n][n] = logits[i]
            if (jcol == n)          { sv.x = lg[i * 2]; sv.y = lg[i * 2 + 1]; }
            else if (jcol + 1 == n) { sv.z = lg[i * 2]; sv.w = lg[i * 2 + 1]; }
        }

        v4f pv;
        const bool k1 = (sv.y + gm.y) > (sv.x + gm.x);
        pv.x = k1 ? 0.0f : 1.0f;  pv.y = k1 ? 1.0f : 0.0f;
        const bool k2 = (sv.w + gm.w) > (sv.z + gm.z);
        pv.z = k2 ? 0.0f : 1.0f;  pv.w = k2 ? 1.0f : 0.0f;

        __builtin_nontemporal_store(sv, &os4[idx]);
        __builtin_nontemporal_store(pv, &op4[idx]);
    }
}

extern "C" void kernel_launch(void* const* d_in, const int* in_sizes, int n_in,
                              void* d_out, int out_size, void* d_ws, size_t ws_size,
                              hipStream_t stream) {
    const float* nodes     = (const float*)d_in[0];
    const float* state     = (const float*)d_in[1];
    const float* W1        = (const float*)d_in[2];
    const float* b1        = (const float*)d_in[3];
    const float* W2        = (const float*)d_in[4];
    const float* b2        = (const float*)d_in[5];
    const int*   num_nodes = (const int*)d_in[6];
    const float* gumbel    = (const float*)d_in[7];

    float* logits = (float*)d_ws;                     // B*N*2 floats = 128 KB
    float* out_s  = (float*)d_out;                    // first output tensor
    float* out_p  = out_s + (size_t)Bq * Nq * Nq * 2; // second output tensor

    logits_kernel<<<Bq * (Nq / JB), 128, 0, stream>>>(
        nodes, W1, b1, W2, b2, num_nodes, logits);

    fill_kernel<<<Bq * Nq, 256, 0, stream>>>(
        state, gumbel, num_nodes, logits, out_s, out_p);
}